// Round 4
// baseline (100.922 us; speedup 1.0000x reference)
//
#include <hip/hip_runtime.h>

// Problem constants (fixed by the reference).
#define B_    8
#define N_    6000
#define C_    21
#define MAXT  200
#define NEGV  -1000000000.0f
#define UCAP  4096      // LDS capacity for unordered candidate keys (M ~2880)
#define CCAP  1024      // chunk capacity (hard); pick targets ~512
#define CTGT  512       // chunk pick target (walk consumes ~235 elements)
#define NBUCK 64        // score buckets = mantissa bits 22..17
#define NTH   1024
#define NENT  (C_ * MAXT)   // 4200 entries per batch
#define NBLK  (B_ * C_)     // 168

// Round-10 lesson (banked): cooperative grid.sync fusion forces device-scope
// coherence across 8 non-coherent per-XCD L2s — WRITE_SIZE 0.66 -> 28.9 MB,
// 216-320 us. Never grid-sync this workload.
// Round-12 lesson: the ~50 us fixed residual is the harness's 256 MiB d_ws
// re-poison fill running at the HBM roofline (~43 us @ 6.2 TB/s) + restores.
// Not controllable from kernel code. Only nms (~40 us) remains a lever.
// Round-13 lesson: bucket-run counting sort (per-wave shfl bitonics, zero
// barriers) replaced the 512-bitonic: -5.0 us (102.5 -> 97.5). Serial-path
// cuts pay ~2x the ISA-table cycle model in this kernel.
// Round-14 lesson (banked): flag-fused merge REGRESSED +7.7 us. Per-block
// device-scope threadfence = full per-XCD L2 writeback x168 + cross-XCD spin
// + acquire invalidation forcing cold HBM re-reads. Kernel-boundary flush
// (done ONCE by the CP) is strictly cheaper. 3-kernel split is the floor.
// Round-15 lesson: IoU area hoist (careaAll/commA) -1.4 us (97.5 -> 96.1).
// Round-16 (this round): (a) hoist the commit-independent intra-batch kill
// matrices OUT of the walk loop into one barrier-free region (killAll[8][64]
// computed right after decode — identical IoU evaluations, identical ballot
// rows, identical guards); (b) fuse decode into the per-wave bucket sort
// (decode from sorted keys still in registers; 3 barriers -> 1). Walk loop
// now carries only committed-check + resolve + 2 barriers per batch.

__device__ __forceinline__ unsigned ford(float f) {
  unsigned u = __float_as_uint(f);
  return (u & 0x80000000u) ? ~u : (u | 0x80000000u);  // order-preserving bits
}
__device__ __forceinline__ float funord(unsigned o) {
  unsigned u = (o & 0x80000000u) ? (o ^ 0x80000000u) : ~o;
  return __uint_as_float(u);
}

// Box decode — expression order matches the numpy reference exactly (absmax 0.0
// verified rounds 1-15); keep fp contract off.
__device__ __forceinline__ float4 decode_box(const float* __restrict__ roi,
                                             const float* __restrict__ deltas,
                                             int b, int n, int c)
{
#pragma clang fp contract(off)
  float4 r = *(const float4*)(roi + ((size_t)b * N_ + n) * 4);
  float4 d = *(const float4*)(deltas + ((size_t)b * N_ + n) * (C_ * 4) + c * 4);
  float d0 = d.x * 0.1f, d1 = d.y * 0.1f, d2 = d.z * 0.2f, d3 = d.w * 0.2f;
  float ah = r.z - r.x, aw = r.w - r.y;
  float acy = r.x + 0.5f * ah, acx = r.y + 0.5f * aw;
  float bh = expf(d2) * ah, bw = expf(d3) * aw;
  float bcy = d0 * ah + acy, bcx = d1 * aw + acx;
  float y1 = bcy - 0.5f * bh, x1 = bcx - 0.5f * bw;
  float y2 = y1 + bh, x2 = x1 + bw;
  y1 = fminf(fmaxf(y1, 0.f), 1.f); x1 = fminf(fmaxf(x1, 0.f), 1.f);
  y2 = fminf(fmaxf(y2, 0.f), 1.f); x2 = fminf(fmaxf(x2, 0.f), 1.f);
  return make_float4(y1, x1, y2, x2);
}

// Area — the exact sub-expression of the reference IoU (contract off).
__device__ __forceinline__ float area_ref(float4 s) {
#pragma clang fp contract(off)
  return fmaxf(s.z - s.x, 0.f) * fmaxf(s.w - s.y, 0.f);
}

// IoU with precomputed operand areas; association preserved exactly:
// ((sa + oa) - inter) + 1e-8, identical float ops to the fused original.
__device__ __forceinline__ float iou_pre(float4 s, float sa, float4 o, float oa) {
#pragma clang fp contract(off)
  float iy1 = fmaxf(s.x, o.x), ix1 = fmaxf(s.y, o.y);
  float iy2 = fminf(s.z, o.z), ix2 = fminf(s.w, o.w);
  float inter = fmaxf(iy2 - iy1, 0.f) * fmaxf(ix2 - ix1, 0.f);
  return inter / (sa + oa - inter + 1e-08f);
}

// Shared-memory block reused by nms and merge (~61 KB).
struct Smem {
  unsigned long long ukeys[UCAP];   // unordered candidate keys / merge keys lo
  unsigned long long cbuf[CCAP];    // chunk in bucket-run order / merge hi
  float4 cboxAll[512];              // decoded chunk boxes / (aliased) merge ranks
  float4 comm[MAXT];                // committed boxes
  float careaAll[512];              // precomputed chunk-box areas (round-15)
  float commA[MAXT];                // precomputed committed areas (round-15)
  unsigned long long killAll[8][64];// hoisted intra-batch kill rows (round-16)
  unsigned long long s_dead[16];
  int hist[NBUCK];
  int ctr[NBUCK];                   // per-bucket scatter cursors (round-13)
  int wcnt[16];
  int s_cnt, s_clen, s_ncomm, s_blo, s_len, s_m, s_mx;
};

// ---- prep: per-anchor argmax (identical expression to the reference:
// strict >, first max wins) + masked-score transpose probsT[b][c][n].
__global__ __launch_bounds__(256) void prep_kernel(
    const float* __restrict__ probs, float* __restrict__ probsT)
{
  int t = blockIdx.x * 256 + threadIdx.x;
  if (t >= B_ * N_) return;
  int b = t / N_, n = t - b * N_;
  const float* pr = probs + (size_t)t * C_;
  float p[C_];
  #pragma unroll
  for (int k = 0; k < C_; ++k) p[k] = pr[k];
  float mx = p[0]; int am = 0;
  #pragma unroll
  for (int k = 1; k < C_; ++k) { if (p[k] > mx) { mx = p[k]; am = k; } }
  float msk = (am != 0) ? 1.0f : 0.0f;
  #pragma unroll
  for (int c = 0; c < C_; ++c)
    probsT[((size_t)b * C_ + c) * N_ + n] = p[c] * msk;   // exact: *1.0f == copy
}

// ---- nms: per-(b,c) block. Round-13 structure (banked, absmax 0.0) with
// round-15 hoisted areas and round-16 hoisted kill matrices + fused decode.
__global__ __launch_bounds__(NTH) void nms_kernel(
    const float* __restrict__ roi, const float* __restrict__ deltas,
    const float* __restrict__ probs, const float* __restrict__ probsT,
    float* __restrict__ sel_val, float* __restrict__ sel_box)
{
#pragma clang fp contract(off)
  __shared__ Smem sm;
  const int bc = blockIdx.x, b = bc / C_, c = bc % C_;
  const int tid = threadIdx.x, lane = tid & 63, wv = tid >> 6;

  if (tid < NBUCK) sm.hist[tid] = 0;
  if (tid == 0) { sm.s_cnt = 0; sm.s_ncomm = 0; }
  __syncthreads();

  int M;
  const float* rowT = probsT ? (probsT + (size_t)bc * N_) : nullptr;
  if (rowT) {
    // Phase 1 (fast path): 6 coalesced loads, ballots, single scan, write.
    float scv[6];
    #pragma unroll
    for (int it = 0; it < 6; ++it) {
      int n = it * NTH + tid;
      scv[it] = (n < N_) ? rowT[n] : 0.f;
    }
    int off[6];
    int wtot = 0;
    #pragma unroll
    for (int it = 0; it < 6; ++it) {
      bool cand = (scv[it] > 0.5f);
      unsigned long long m = __ballot(cand);
      off[it] = wtot + __popcll(m & ((1ULL << lane) - 1ULL));
      wtot += __popcll(m);
    }
    if (lane == 0) sm.wcnt[wv] = wtot;
    __syncthreads();
    int wbase = 0, mtot = 0;
    #pragma unroll
    for (int w = 0; w < 16; ++w) {
      int t2 = sm.wcnt[w];
      if (w < wv) wbase += t2;
      mtot += t2;
    }
    #pragma unroll
    for (int it = 0; it < 6; ++it) {
      if (scv[it] > 0.5f) {
        int pos = wbase + off[it];
        if (pos < UCAP) {
          unsigned hi = ford(scv[it]);
          int n = it * NTH + tid;
          sm.ukeys[pos] = ((unsigned long long)hi << 32) |
                          (unsigned)(0xFFFFFFFFu - (unsigned)n);
          atomicAdd(&sm.hist[(hi >> 17) & (NBUCK - 1)], 1);
        }
      }
    }
    __syncthreads();
    M = mtot < UCAP ? mtot : UCAP;
  } else {
    // Fallback (small-ws): inline argmax scan (round-8 path).
    for (int base0 = 0; base0 < N_; base0 += NTH) {
      int n = base0 + tid;
      bool cand = false;
      float sc = 0.f;
      if (n < N_) {
        const float* pr = probs + ((size_t)b * N_ + n) * C_;
        float mx = pr[0]; int am = 0;
        #pragma unroll
        for (int k = 1; k < C_; ++k) { float v = pr[k]; if (v > mx) { mx = v; am = k; } }
        if (am != 0) sc = pr[c];
        cand = (sc > 0.5f);
      }
      unsigned long long m = __ballot(cand);
      int wcnt2 = __popcll(m);
      int bslot = 0;
      if (lane == 0 && wcnt2) bslot = atomicAdd(&sm.s_cnt, wcnt2);
      bslot = __shfl(bslot, 0);
      if (cand) {
        int pos = bslot + __popcll(m & ((1ULL << lane) - 1ULL));
        if (pos < UCAP) {
          unsigned hi = ford(sc);
          sm.ukeys[pos] = ((unsigned long long)hi << 32) |
                          (unsigned)(0xFFFFFFFFu - (unsigned)n);
          atomicAdd(&sm.hist[(hi >> 17) & (NBUCK - 1)], 1);
        }
      }
    }
    __syncthreads();
    M = sm.s_cnt < UCAP ? sm.s_cnt : UCAP;
  }

  float* sv = sel_val + (size_t)bc * MAXT;
  float* sb = sel_box + (size_t)bc * MAXT * 4;

  // Phase 2: chunked bucket-run sort + walk.
  int bhi = NBUCK - 1;
  while (true) {
    if (sm.s_ncomm >= MAXT || bhi < 0) break;

    // wave-parallel chunk pick (wave 0): lane l holds hist[bhi-l]; inclusive
    // shfl scan -> prefix sums P_l; take m = #(P <= CTGT) buckets (>=1; clamp
    // to available). Monotone prefix => identical (blo,len) to serial loop.
    // Round-13 additions: per-bucket scatter bases ctr[bk] = P_l - h_l
    // (exclusive prefix in bucket-desc order) and max bucket length s_mx.
    if (wv == 0) {
      int h = (lane <= bhi) ? sm.hist[bhi - lane] : 0;
      int p = h;
      #pragma unroll
      for (int d = 1; d < 64; d <<= 1) {
        int o = __shfl_up(p, d);
        if (lane >= d) p += o;
      }
      unsigned long long ok = __ballot(p <= CTGT);
      int m = __popcll(ok);
      if (m == 0) m = 1;                 // first bucket alone > CTGT: take it
      if (m > bhi + 1) m = bhi + 1;      // clamp to available buckets
      int len = __shfl(p, m - 1);
      if (lane < m) sm.ctr[bhi - lane] = p - h;   // bucket base (desc runs)
      int hv = (lane < m) ? h : 0;
      #pragma unroll
      for (int d = 1; d < 64; d <<= 1) hv = max(hv, __shfl_xor(hv, d));
      if (lane == 0) {
        sm.s_blo = bhi - (m - 1); sm.s_len = len; sm.s_clen = 0;
        sm.s_m = m; sm.s_mx = hv;
      }
    }
    __syncthreads();
    int blo = sm.s_blo;
    if (sm.s_len == 0) break;
    int mbk = sm.s_m, mxb = sm.s_mx;

    // scatter chunk members from unordered keys straight into their bucket's
    // region (counting sort by bucket; within-bucket order random — the
    // per-bucket sort below fixes it).
    for (int i = tid; i < M; i += NTH) {
      unsigned long long kk = sm.ukeys[i];
      int bk = (int)((kk >> 49) & (NBUCK - 1));
      if (bk >= blo && bk <= bhi) {
        int slot = atomicAdd(&sm.ctr[bk], 1);
        if (slot < CCAP) sm.cbuf[slot] = kk;
      }
    }
    __syncthreads();
    int alen = sm.s_len < CCAP ? sm.s_len : CCAP;

    if (alen > 0) {
      if (alen <= 512 && mxb <= 128) {
        // bucket-run sort + fused decode: wave w sorts buckets j = w, w+16,...
        // shfl-only bitonic, then decodes its bucket's boxes straight from the
        // sorted keys still in registers (gather latency overlaps siblings).
        for (int j = wv; j < mbk; j += 16) {
          int bk = bhi - j;
          int len = sm.hist[bk];
          if (len <= 0) continue;
          int base = sm.ctr[bk] - len;    // ctr advanced to base+len by scatter
          if (len <= 64) {
            unsigned long long v = (lane < len) ? sm.cbuf[base + lane] : 0ULL;
            #pragma unroll
            for (int k = 2; k <= 64; k <<= 1) {
              for (int jj = k >> 1; jj > 0; jj >>= 1) {
                unsigned long long w = __shfl_xor(v, jj);
                bool takeMax = ((lane & jj) == 0) == ((lane & k) == 0);
                if ((w > v) == takeMax) v = w;
              }
            }
            if (lane < len) {
              sm.cbuf[base + lane] = v;
              int n = (int)(0xFFFFFFFFu - (unsigned)(v & 0xFFFFFFFFull));
              float4 bb = decode_box(roi, deltas, b, n, c);
              sm.cboxAll[base + lane] = bb;
              sm.careaAll[base + lane] = area_ref(bb);
            }
          } else {
            // 128-element bitonic, 2 elems/lane: e0=lane (v0), e1=lane+64 (v1).
            unsigned long long v0 = (lane < len) ? sm.cbuf[base + lane] : 0ULL;
            unsigned long long v1 = (64 + lane < len) ? sm.cbuf[base + 64 + lane] : 0ULL;
            #pragma unroll
            for (int k = 2; k <= 128; k <<= 1) {
              for (int jj = k >> 1; jj > 0; jj >>= 1) {
                if (jj == 64) {
                  // partner is the other register of the same lane (k==128).
                  unsigned long long a = (v0 > v1) ? v0 : v1;
                  unsigned long long bmin = (v0 > v1) ? v1 : v0;
                  v0 = a; v1 = bmin;      // takeMax0 true, takeMax1 false
                } else {
                  unsigned long long w0 = __shfl_xor(v0, jj);
                  unsigned long long w1 = __shfl_xor(v1, jj);
                  bool e0k = ((lane & k) == 0);
                  bool e1k = (((lane + 64) & k) == 0);
                  bool jz = ((lane & jj) == 0);
                  bool tm0 = (jz == e0k);
                  bool tm1 = (jz == e1k);
                  if ((w0 > v0) == tm0) v0 = w0;
                  if ((w1 > v1) == tm1) v1 = w1;
                }
              }
            }
            if (lane < len) {
              sm.cbuf[base + lane] = v0;
              int n = (int)(0xFFFFFFFFu - (unsigned)(v0 & 0xFFFFFFFFull));
              float4 bb = decode_box(roi, deltas, b, n, c);
              sm.cboxAll[base + lane] = bb;
              sm.careaAll[base + lane] = area_ref(bb);
            }
            if (64 + lane < len) {
              sm.cbuf[base + 64 + lane] = v1;
              int n = (int)(0xFFFFFFFFu - (unsigned)(v1 & 0xFFFFFFFFull));
              float4 bb = decode_box(roi, deltas, b, n, c);
              sm.cboxAll[base + 64 + lane] = bb;
              sm.careaAll[base + 64 + lane] = area_ref(bb);
            }
          }
        }
        __syncthreads();
      } else {
        // in-place full bitonic fallback (alen > 512 or a bucket > 128:
        // statistically never with this data; kept for exactness safety).
        int SORTP = 64;
        while (SORTP < alen) SORTP <<= 1;
        unsigned long long v = (tid < alen) ? sm.cbuf[tid] : 0ULL;
        for (int k = 2; k <= SORTP; k <<= 1) {
          for (int j = k >> 1; j > 0; j >>= 1) {
            bool takeMax = ((tid & j) == 0) == ((tid & k) == 0);
            unsigned long long w;
            if (j >= 64) {
              __syncthreads(); if (tid < SORTP) sm.cbuf[tid] = v; __syncthreads();
              w = sm.cbuf[tid ^ j];
            } else {
              w = __shfl_xor(v, j);
            }
            if (tid < SORTP && (w > v) == takeMax) v = w;
          }
        }
        __syncthreads();
        if (tid < SORTP) sm.cbuf[tid] = v;
        __syncthreads();
        // separate decode for the fallback path
        if (tid < alen && tid < 512) {
          int n = (int)(0xFFFFFFFFu - (unsigned)(sm.cbuf[tid] & 0xFFFFFFFFull));
          float4 bb = decode_box(roi, deltas, b, n, c);
          sm.cboxAll[tid] = bb;
          sm.careaAll[tid] = area_ref(bb);
        }
        __syncthreads();
      }

      int wlen = alen < 512 ? alen : 512;   // decoded prefix (alen<=512 always)

      // round-16: hoisted kill matrices — commit-independent, barrier-free.
      // Identical IoU evaluations / ballot rows / guards as the in-loop
      // version; only the execution site moved.
      {
        int nbat = (wlen + 63) >> 6;
        for (int bi = 0; bi < nbat; ++bi) {
          int bst = bi << 6;
          int bs = min(64, wlen - bst);
          float4 ib = sm.cboxAll[bst + lane];
          float ia = sm.careaAll[bst + lane];
          #pragma unroll
          for (int r = 0; r < 4; ++r) {
            int j = (wv << 2) | r;
            float4 jb4 = sm.cboxAll[bst + j];
            float ja = sm.careaAll[bst + j];
            bool kf = (j < bs) && (lane < bs) && (lane > j) &&
                      (iou_pre(jb4, ja, ib, ia) > 0.5f);
            unsigned long long rowm = __ballot(kf);
            if (lane == 0) sm.killAll[bi][j] = rowm;
          }
        }
      }
      // (no barrier needed here: first walk barrier orders killAll writes
      // before wave-0's resolve reads)

      // walk the sorted chunk in batches of 64 (2 barriers per batch;
      // per-batch work is now only committed-check + resolve)
      int start = 0, bi = 0;
      while (true) {
        int nc = sm.s_ncomm;
        if (nc >= MAXT || start >= wlen) break;
        int bs = min(64, wlen - start);

        float4 ib = sm.cboxAll[start + lane];
        float ia = sm.careaAll[start + lane];
        {
          bool dead = false;
          if (lane < bs) {
            for (int jc = wv; jc < nc; jc += 16) {
              if (iou_pre(sm.comm[jc], sm.commA[jc], ib, ia) > 0.5f) { dead = true; break; }
            }
          }
          unsigned long long dm = __ballot(dead);
          if (lane == 0) sm.s_dead[wv] = dm;
        }
        __syncthreads();

        // resolve in wave 0: bit-transpose + peeling (ballot-pure; equivalent
        // to the serial walk by greedy-prefix induction; exact MAXT trunc).
        if (wv == 0) {
          unsigned long long sup = sm.s_dead[0];
          #pragma unroll
          for (int w2 = 1; w2 < 16; ++w2) sup |= sm.s_dead[w2];
          unsigned long long row = sm.killAll[bi][lane];
          #pragma unroll
          for (int s5 = 0; s5 < 6; ++s5) {
            const unsigned long long Ms[6] = {
              0x5555555555555555ULL, 0x3333333333333333ULL,
              0x0F0F0F0F0F0F0F0FULL, 0x00FF00FF00FF00FFULL,
              0x0000FFFF0000FFFFULL, 0x00000000FFFFFFFFULL };
            int d = 1 << s5;
            unsigned long long other = __shfl_xor(row, d);
            unsigned long long Mk = Ms[s5];
            row = ((lane & d) == 0) ? ((row & Mk) | ((other & Mk) << d))
                                    : ((row & ~Mk) | ((other & ~Mk) >> d));
          }
          unsigned long long col = row;   // col_i = {j<i : j would kill i}

          unsigned long long alive = ~sup;
          if (bs < 64) alive &= (1ULL << bs) - 1ULL;
          unsigned long long pend = alive, chosen = 0ULL;
          while (pend) {
            bool rdy_b = ((col & pend) == 0ULL);
            unsigned long long rdy = __ballot(rdy_b) & pend;
            bool kld_b = ((col & chosen) != 0ULL);
            unsigned long long kl = __ballot(kld_b);
            chosen |= rdy & ~kl;
            pend &= ~rdy;
          }
          int take = MAXT - nc;
          if (__popcll(chosen) > take) {
            bool keep = ((chosen >> lane) & 1ULL) &&
                        (__popcll(chosen & ((1ULL << lane) - 1ULL)) < take);
            chosen = __ballot(keep);
          }
          if ((chosen >> lane) & 1ULL) {
            int rnk = nc + __popcll(chosen & ((1ULL << lane) - 1ULL));
            float4 bb2 = sm.cboxAll[start + lane];
            sm.comm[rnk] = bb2;
            sm.commA[rnk] = sm.careaAll[start + lane];
            sv[rnk] = funord((unsigned)(sm.cbuf[start + lane] >> 32));
            sb[(size_t)rnk * 4 + 0] = bb2.x; sb[(size_t)rnk * 4 + 1] = bb2.y;
            sb[(size_t)rnk * 4 + 2] = bb2.z; sb[(size_t)rnk * 4 + 3] = bb2.w;
          }
          if (lane == 0) sm.s_ncomm = nc + __popcll(chosen);
        }
        __syncthreads();
        start += bs; ++bi;
      }
    }
    bhi = blo - 1;
  }

  // remaining steps invalid -> sel_val = NEG (boxes never read for these)
  int T = sm.s_ncomm;
  for (int j2 = T + tid; j2 < MAXT; j2 += NTH) sv[j2] = NEGV;
}

// ---- merge (fused rank+scatter, round-11/12 verbatim): block (b,sc) loads
// all 4200 batch keys into LDS; 5 threads per entry split the 21 class binary
// searches; integer LDS atomicAdd partial sums (order-independent => exact,
// deterministic); 200 threads scatter. rank = sum over classes of
// count(key > mykey); ranks are a permutation of 0..4199.
__global__ __launch_bounds__(NTH) void merge2_kernel(
    const float* __restrict__ sel_val, const float* __restrict__ sel_box,
    float* __restrict__ out)
{
  __shared__ Smem sm;
  const int bc = blockIdx.x;
  const int b = bc / C_, sc = bc % C_;
  const int tid = threadIdx.x;
  int* s_rank = reinterpret_cast<int*>(sm.cboxAll);   // aliased scratch

  for (int i = tid; i < NENT; i += NTH) {
    float v = sel_val[(size_t)b * NENT + i];
    unsigned long long key = ((unsigned long long)ford(v) << 32) |
                             (unsigned)(0xFFFFFFFFu - (unsigned)i);
    if (i < UCAP) sm.ukeys[i] = key; else sm.cbuf[i - UCAP] = key;
  }
  if (tid < MAXT) s_rank[tid] = 0;
  __syncthreads();

  auto klds = [&](int i) -> unsigned long long {
    return (i < UCAP) ? sm.ukeys[i] : sm.cbuf[i - UCAP];
  };

  if (tid < 1000) {
    int q = tid / MAXT, t = tid - q * MAXT;   // q in [0,5), t in [0,200)
    int e = sc * MAXT + t;
    unsigned long long mykey = klds(e);
    int part = 0;
    for (int cc = q; cc < C_; cc += 5) {
      int lo = 0, hi = MAXT;
      while (lo < hi) {
        int mid = (lo + hi) >> 1;
        if (klds(cc * MAXT + mid) > mykey) lo = mid + 1; else hi = mid;
      }
      part += lo;
    }
    atomicAdd(&s_rank[t], part);
  }
  __syncthreads();

  if (tid < MAXT) {
    int t = tid;
    int e = sc * MAXT + t;
    int rank = s_rank[t];
    if (rank < MAXT) {
      float* obx = out + (size_t)b * MAXT * 4;                       // bboxes
      float* olb = out + (size_t)B_ * MAXT * 4 + (size_t)b * MAXT;   // labels
      float* osc = out + (size_t)B_ * MAXT * 5 + (size_t)b * MAXT;   // scores
      float v = funord((unsigned)(klds(e) >> 32));
      if (v > NEGV * 0.5f) {
        osc[rank] = v;
        olb[rank] = (float)sc;
        const float* bp = sel_box + ((size_t)b * NENT + e) * 4;
        obx[rank * 4 + 0] = bp[0]; obx[rank * 4 + 1] = bp[1];
        obx[rank * 4 + 2] = bp[2]; obx[rank * 4 + 3] = bp[3];
      } else {
        osc[rank] = 0.f; olb[rank] = 0.f;
        obx[rank * 4 + 0] = 0.f; obx[rank * 4 + 1] = 0.f;
        obx[rank * 4 + 2] = 0.f; obx[rank * 4 + 3] = 0.f;
      }
    }
  }
}

extern "C" void kernel_launch(void* const* d_in, const int* in_sizes, int n_in,
                              void* d_out, int out_size, void* d_ws, size_t ws_size,
                              hipStream_t stream)
{
  const float* roi    = (const float*)d_in[0];  // (8,6000,4)
  const float* deltas = (const float*)d_in[1];  // (8,6000,84)
  const float* probs  = (const float*)d_in[2];  // (8,6000,21)
  float* out = (float*)d_out;                   // 6400 + 1600 + 1600 floats
  float* ws  = (float*)d_ws;

  // ws layout (floats): sel_val[33600] | sel_box[134400] | probsT[1008000]
  float* sel_val = ws;
  float* sel_box = ws + (size_t)B_ * NENT;
  float* probsT  = ws + (size_t)B_ * NENT * 5;
  size_t need_mid = ((size_t)B_ * NENT * 5 + (size_t)B_ * C_ * N_) * sizeof(float);
  bool haveT = (ws_size >= need_mid);

  const float* probsT_arg = haveT ? probsT : nullptr;
  if (haveT)
    prep_kernel<<<dim3((B_ * N_ + 255) / 256), dim3(256), 0, stream>>>(probs, probsT);
  nms_kernel<<<dim3(NBLK), dim3(NTH), 0, stream>>>(
      roi, deltas, probs, probsT_arg, sel_val, sel_box);
  merge2_kernel<<<dim3(NBLK), dim3(NTH), 0, stream>>>(sel_val, sel_box, out);
}

// Round 5
// 95.805 us; speedup vs baseline: 1.0534x; 1.0534x over previous
//
#include <hip/hip_runtime.h>

// Problem constants (fixed by the reference).
#define B_    8
#define N_    6000
#define C_    21
#define MAXT  200
#define NEGV  -1000000000.0f
#define UCAP  4096      // LDS capacity for unordered candidate keys (M ~2880)
#define CCAP  1024      // chunk capacity (hard); pick targets ~512
#define CTGT  512       // chunk pick target (walk consumes ~235 elements)
#define NBUCK 64        // score buckets = mantissa bits 22..17
#define NTH   1024
#define NENT  (C_ * MAXT)   // 4200 entries per batch
#define NBLK  (B_ * C_)     // 168

// Round-10 lesson (banked): cooperative grid.sync fusion forces device-scope
// coherence across 8 non-coherent per-XCD L2s — WRITE_SIZE 0.66 -> 28.9 MB,
// 216-320 us. Never grid-sync this workload.
// Round-12 lesson: the ~50 us fixed residual is the harness's 256 MiB d_ws
// re-poison fill running at the HBM roofline (~43 us @ 6.2 TB/s) + restores.
// Not controllable from kernel code. Only nms (~40 us) remains a lever.
// Round-13 lesson: bucket-run counting sort (per-wave shfl bitonics, zero
// barriers) replaced the 512-bitonic: -5.0 us (102.5 -> 97.5). Serial-path
// cuts pay ~2x the ISA-table cycle model in this kernel.
// Round-14 lesson (banked): flag-fused merge REGRESSED +7.7 us. Per-block
// device-scope threadfence = full per-XCD L2 writeback x168 + cross-XCD spin
// + acquire invalidation forcing cold HBM re-reads. Kernel-boundary flush
// (done ONCE by the CP) is strictly cheaper. 3-kernel split is the floor.
// Round-15 lesson: IoU area hoist (careaAll/commA) -1.4 us (97.5 -> 96.1).
// Round-16 lesson (banked): speculative kill-matrix hoist over the FULL
// 512 decoded prefix REGRESSED ~2 us — the walk terminates at ~235 elems,
// so the hoist doubles kill work. Lazy per-batch kill (computed only for
// batches actually walked) is correct. Machine noise also ~±2.5% between
// holds: compare via fill-dispatch times (43.2 us nominal) before judging.
// Round-17 (this round): round-15 structure + round-16's work-neutral piece
// only (decode fused into the per-wave bucket sort: 3 barriers -> 1, zero
// extra work). Kill matrix back in-loop (lazy).

__device__ __forceinline__ unsigned ford(float f) {
  unsigned u = __float_as_uint(f);
  return (u & 0x80000000u) ? ~u : (u | 0x80000000u);  // order-preserving bits
}
__device__ __forceinline__ float funord(unsigned o) {
  unsigned u = (o & 0x80000000u) ? (o ^ 0x80000000u) : ~o;
  return __uint_as_float(u);
}

// Box decode — expression order matches the numpy reference exactly (absmax 0.0
// verified rounds 1-16); keep fp contract off.
__device__ __forceinline__ float4 decode_box(const float* __restrict__ roi,
                                             const float* __restrict__ deltas,
                                             int b, int n, int c)
{
#pragma clang fp contract(off)
  float4 r = *(const float4*)(roi + ((size_t)b * N_ + n) * 4);
  float4 d = *(const float4*)(deltas + ((size_t)b * N_ + n) * (C_ * 4) + c * 4);
  float d0 = d.x * 0.1f, d1 = d.y * 0.1f, d2 = d.z * 0.2f, d3 = d.w * 0.2f;
  float ah = r.z - r.x, aw = r.w - r.y;
  float acy = r.x + 0.5f * ah, acx = r.y + 0.5f * aw;
  float bh = expf(d2) * ah, bw = expf(d3) * aw;
  float bcy = d0 * ah + acy, bcx = d1 * aw + acx;
  float y1 = bcy - 0.5f * bh, x1 = bcx - 0.5f * bw;
  float y2 = y1 + bh, x2 = x1 + bw;
  y1 = fminf(fmaxf(y1, 0.f), 1.f); x1 = fminf(fmaxf(x1, 0.f), 1.f);
  y2 = fminf(fmaxf(y2, 0.f), 1.f); x2 = fminf(fmaxf(x2, 0.f), 1.f);
  return make_float4(y1, x1, y2, x2);
}

// Area — the exact sub-expression of the reference IoU (contract off).
__device__ __forceinline__ float area_ref(float4 s) {
#pragma clang fp contract(off)
  return fmaxf(s.z - s.x, 0.f) * fmaxf(s.w - s.y, 0.f);
}

// IoU with precomputed operand areas; association preserved exactly:
// ((sa + oa) - inter) + 1e-8, identical float ops to the fused original.
__device__ __forceinline__ float iou_pre(float4 s, float sa, float4 o, float oa) {
#pragma clang fp contract(off)
  float iy1 = fmaxf(s.x, o.x), ix1 = fmaxf(s.y, o.y);
  float iy2 = fminf(s.z, o.z), ix2 = fminf(s.w, o.w);
  float inter = fmaxf(iy2 - iy1, 0.f) * fmaxf(ix2 - ix1, 0.f);
  return inter / (sa + oa - inter + 1e-08f);
}

// Shared-memory block reused by nms and merge (~57 KB).
struct Smem {
  unsigned long long ukeys[UCAP];   // unordered candidate keys / merge keys lo
  unsigned long long cbuf[CCAP];    // chunk in bucket-run order / merge hi
  float4 cboxAll[512];              // decoded chunk boxes / (aliased) merge ranks
  float4 comm[MAXT];                // committed boxes
  float careaAll[512];              // precomputed chunk-box areas (round-15)
  float commA[MAXT];                // precomputed committed areas (round-15)
  unsigned long long kill[64];
  unsigned long long s_dead[16];
  int hist[NBUCK];
  int ctr[NBUCK];                   // per-bucket scatter cursors (round-13)
  int wcnt[16];
  int s_cnt, s_clen, s_ncomm, s_blo, s_len, s_m, s_mx;
};

// ---- prep: per-anchor argmax (identical expression to the reference:
// strict >, first max wins) + masked-score transpose probsT[b][c][n].
__global__ __launch_bounds__(256) void prep_kernel(
    const float* __restrict__ probs, float* __restrict__ probsT)
{
  int t = blockIdx.x * 256 + threadIdx.x;
  if (t >= B_ * N_) return;
  int b = t / N_, n = t - b * N_;
  const float* pr = probs + (size_t)t * C_;
  float p[C_];
  #pragma unroll
  for (int k = 0; k < C_; ++k) p[k] = pr[k];
  float mx = p[0]; int am = 0;
  #pragma unroll
  for (int k = 1; k < C_; ++k) { if (p[k] > mx) { mx = p[k]; am = k; } }
  float msk = (am != 0) ? 1.0f : 0.0f;
  #pragma unroll
  for (int c = 0; c < C_; ++c)
    probsT[((size_t)b * C_ + c) * N_ + n] = p[c] * msk;   // exact: *1.0f == copy
}

// ---- nms: per-(b,c) block. Round-15 structure (banked, absmax 0.0) with
// round-17 fused sort+decode; kill matrix lazy in-loop.
__global__ __launch_bounds__(NTH) void nms_kernel(
    const float* __restrict__ roi, const float* __restrict__ deltas,
    const float* __restrict__ probs, const float* __restrict__ probsT,
    float* __restrict__ sel_val, float* __restrict__ sel_box)
{
#pragma clang fp contract(off)
  __shared__ Smem sm;
  const int bc = blockIdx.x, b = bc / C_, c = bc % C_;
  const int tid = threadIdx.x, lane = tid & 63, wv = tid >> 6;

  if (tid < NBUCK) sm.hist[tid] = 0;
  if (tid == 0) { sm.s_cnt = 0; sm.s_ncomm = 0; }
  __syncthreads();

  int M;
  const float* rowT = probsT ? (probsT + (size_t)bc * N_) : nullptr;
  if (rowT) {
    // Phase 1 (fast path): 6 coalesced loads, ballots, single scan, write.
    float scv[6];
    #pragma unroll
    for (int it = 0; it < 6; ++it) {
      int n = it * NTH + tid;
      scv[it] = (n < N_) ? rowT[n] : 0.f;
    }
    int off[6];
    int wtot = 0;
    #pragma unroll
    for (int it = 0; it < 6; ++it) {
      bool cand = (scv[it] > 0.5f);
      unsigned long long m = __ballot(cand);
      off[it] = wtot + __popcll(m & ((1ULL << lane) - 1ULL));
      wtot += __popcll(m);
    }
    if (lane == 0) sm.wcnt[wv] = wtot;
    __syncthreads();
    int wbase = 0, mtot = 0;
    #pragma unroll
    for (int w = 0; w < 16; ++w) {
      int t2 = sm.wcnt[w];
      if (w < wv) wbase += t2;
      mtot += t2;
    }
    #pragma unroll
    for (int it = 0; it < 6; ++it) {
      if (scv[it] > 0.5f) {
        int pos = wbase + off[it];
        if (pos < UCAP) {
          unsigned hi = ford(scv[it]);
          int n = it * NTH + tid;
          sm.ukeys[pos] = ((unsigned long long)hi << 32) |
                          (unsigned)(0xFFFFFFFFu - (unsigned)n);
          atomicAdd(&sm.hist[(hi >> 17) & (NBUCK - 1)], 1);
        }
      }
    }
    __syncthreads();
    M = mtot < UCAP ? mtot : UCAP;
  } else {
    // Fallback (small-ws): inline argmax scan (round-8 path).
    for (int base0 = 0; base0 < N_; base0 += NTH) {
      int n = base0 + tid;
      bool cand = false;
      float sc = 0.f;
      if (n < N_) {
        const float* pr = probs + ((size_t)b * N_ + n) * C_;
        float mx = pr[0]; int am = 0;
        #pragma unroll
        for (int k = 1; k < C_; ++k) { float v = pr[k]; if (v > mx) { mx = v; am = k; } }
        if (am != 0) sc = pr[c];
        cand = (sc > 0.5f);
      }
      unsigned long long m = __ballot(cand);
      int wcnt2 = __popcll(m);
      int bslot = 0;
      if (lane == 0 && wcnt2) bslot = atomicAdd(&sm.s_cnt, wcnt2);
      bslot = __shfl(bslot, 0);
      if (cand) {
        int pos = bslot + __popcll(m & ((1ULL << lane) - 1ULL));
        if (pos < UCAP) {
          unsigned hi = ford(sc);
          sm.ukeys[pos] = ((unsigned long long)hi << 32) |
                          (unsigned)(0xFFFFFFFFu - (unsigned)n);
          atomicAdd(&sm.hist[(hi >> 17) & (NBUCK - 1)], 1);
        }
      }
    }
    __syncthreads();
    M = sm.s_cnt < UCAP ? sm.s_cnt : UCAP;
  }

  float* sv = sel_val + (size_t)bc * MAXT;
  float* sb = sel_box + (size_t)bc * MAXT * 4;

  // Phase 2: chunked bucket-run sort + walk.
  int bhi = NBUCK - 1;
  while (true) {
    if (sm.s_ncomm >= MAXT || bhi < 0) break;

    // wave-parallel chunk pick (wave 0): lane l holds hist[bhi-l]; inclusive
    // shfl scan -> prefix sums P_l; take m = #(P <= CTGT) buckets (>=1; clamp
    // to available). Monotone prefix => identical (blo,len) to serial loop.
    // Round-13 additions: per-bucket scatter bases ctr[bk] = P_l - h_l
    // (exclusive prefix in bucket-desc order) and max bucket length s_mx.
    if (wv == 0) {
      int h = (lane <= bhi) ? sm.hist[bhi - lane] : 0;
      int p = h;
      #pragma unroll
      for (int d = 1; d < 64; d <<= 1) {
        int o = __shfl_up(p, d);
        if (lane >= d) p += o;
      }
      unsigned long long ok = __ballot(p <= CTGT);
      int m = __popcll(ok);
      if (m == 0) m = 1;                 // first bucket alone > CTGT: take it
      if (m > bhi + 1) m = bhi + 1;      // clamp to available buckets
      int len = __shfl(p, m - 1);
      if (lane < m) sm.ctr[bhi - lane] = p - h;   // bucket base (desc runs)
      int hv = (lane < m) ? h : 0;
      #pragma unroll
      for (int d = 1; d < 64; d <<= 1) hv = max(hv, __shfl_xor(hv, d));
      if (lane == 0) {
        sm.s_blo = bhi - (m - 1); sm.s_len = len; sm.s_clen = 0;
        sm.s_m = m; sm.s_mx = hv;
      }
    }
    __syncthreads();
    int blo = sm.s_blo;
    if (sm.s_len == 0) break;
    int mbk = sm.s_m, mxb = sm.s_mx;

    // scatter chunk members from unordered keys straight into their bucket's
    // region (counting sort by bucket; within-bucket order random — the
    // per-bucket sort below fixes it).
    for (int i = tid; i < M; i += NTH) {
      unsigned long long kk = sm.ukeys[i];
      int bk = (int)((kk >> 49) & (NBUCK - 1));
      if (bk >= blo && bk <= bhi) {
        int slot = atomicAdd(&sm.ctr[bk], 1);
        if (slot < CCAP) sm.cbuf[slot] = kk;
      }
    }
    __syncthreads();
    int alen = sm.s_clen < CCAP ? sm.s_len : sm.s_len;  // == s_len (<=CCAP by pick)
    alen = alen < CCAP ? alen : CCAP;

    if (alen > 0) {
      if (alen <= 512 && mxb <= 128) {
        // bucket-run sort + fused decode (round-17): wave w sorts buckets
        // j = w, w+16, ... shfl-only bitonic, then decodes its bucket's boxes
        // straight from the sorted keys still in registers.
        for (int j = wv; j < mbk; j += 16) {
          int bk = bhi - j;
          int len = sm.hist[bk];
          if (len <= 0) continue;
          int base = sm.ctr[bk] - len;    // ctr advanced to base+len by scatter
          if (len <= 64) {
            unsigned long long v = (lane < len) ? sm.cbuf[base + lane] : 0ULL;
            #pragma unroll
            for (int k = 2; k <= 64; k <<= 1) {
              for (int jj = k >> 1; jj > 0; jj >>= 1) {
                unsigned long long w = __shfl_xor(v, jj);
                bool takeMax = ((lane & jj) == 0) == ((lane & k) == 0);
                if ((w > v) == takeMax) v = w;
              }
            }
            if (lane < len) {
              sm.cbuf[base + lane] = v;
              int n = (int)(0xFFFFFFFFu - (unsigned)(v & 0xFFFFFFFFull));
              float4 bb = decode_box(roi, deltas, b, n, c);
              sm.cboxAll[base + lane] = bb;
              sm.careaAll[base + lane] = area_ref(bb);
            }
          } else {
            // 128-element bitonic, 2 elems/lane: e0=lane (v0), e1=lane+64 (v1).
            unsigned long long v0 = (lane < len) ? sm.cbuf[base + lane] : 0ULL;
            unsigned long long v1 = (64 + lane < len) ? sm.cbuf[base + 64 + lane] : 0ULL;
            #pragma unroll
            for (int k = 2; k <= 128; k <<= 1) {
              for (int jj = k >> 1; jj > 0; jj >>= 1) {
                if (jj == 64) {
                  // partner is the other register of the same lane (k==128).
                  unsigned long long a = (v0 > v1) ? v0 : v1;
                  unsigned long long bmin = (v0 > v1) ? v1 : v0;
                  v0 = a; v1 = bmin;      // takeMax0 true, takeMax1 false
                } else {
                  unsigned long long w0 = __shfl_xor(v0, jj);
                  unsigned long long w1 = __shfl_xor(v1, jj);
                  bool e0k = ((lane & k) == 0);
                  bool e1k = (((lane + 64) & k) == 0);
                  bool jz = ((lane & jj) == 0);
                  bool tm0 = (jz == e0k);
                  bool tm1 = (jz == e1k);
                  if ((w0 > v0) == tm0) v0 = w0;
                  if ((w1 > v1) == tm1) v1 = w1;
                }
              }
            }
            if (lane < len) {
              sm.cbuf[base + lane] = v0;
              int n = (int)(0xFFFFFFFFu - (unsigned)(v0 & 0xFFFFFFFFull));
              float4 bb = decode_box(roi, deltas, b, n, c);
              sm.cboxAll[base + lane] = bb;
              sm.careaAll[base + lane] = area_ref(bb);
            }
            if (64 + lane < len) {
              sm.cbuf[base + 64 + lane] = v1;
              int n = (int)(0xFFFFFFFFu - (unsigned)(v1 & 0xFFFFFFFFull));
              float4 bb = decode_box(roi, deltas, b, n, c);
              sm.cboxAll[base + 64 + lane] = bb;
              sm.careaAll[base + 64 + lane] = area_ref(bb);
            }
          }
        }
        __syncthreads();
      } else {
        // in-place full bitonic fallback (alen > 512 or a bucket > 128:
        // statistically never with this data; kept for exactness safety).
        int SORTP = 64;
        while (SORTP < alen) SORTP <<= 1;
        unsigned long long v = (tid < alen) ? sm.cbuf[tid] : 0ULL;
        for (int k = 2; k <= SORTP; k <<= 1) {
          for (int j = k >> 1; j > 0; j >>= 1) {
            bool takeMax = ((tid & j) == 0) == ((tid & k) == 0);
            unsigned long long w;
            if (j >= 64) {
              __syncthreads(); if (tid < SORTP) sm.cbuf[tid] = v; __syncthreads();
              w = sm.cbuf[tid ^ j];
            } else {
              w = __shfl_xor(v, j);
            }
            if (tid < SORTP && (w > v) == takeMax) v = w;
          }
        }
        __syncthreads();
        if (tid < SORTP) sm.cbuf[tid] = v;
        __syncthreads();
        // separate decode for the fallback path
        if (tid < alen && tid < 512) {
          int n = (int)(0xFFFFFFFFu - (unsigned)(sm.cbuf[tid] & 0xFFFFFFFFull));
          float4 bb = decode_box(roi, deltas, b, n, c);
          sm.cboxAll[tid] = bb;
          sm.careaAll[tid] = area_ref(bb);
        }
        __syncthreads();
      }

      // walk the sorted chunk in batches of 64 (2 barriers per batch;
      // kill matrix computed lazily per batch — round-16 lesson).
      int start = 0;
      int wlen = alen < 512 ? alen : 512;   // decoded prefix (alen<=512 always)
      while (true) {
        int nc = sm.s_ncomm;
        if (nc >= MAXT || start >= wlen) break;
        int bs = min(64, wlen - start);

        float4 ib = sm.cboxAll[start + lane];
        float ia = sm.careaAll[start + lane];
        #pragma unroll
        for (int r = 0; r < 4; ++r) {
          int j = (wv << 2) | r;
          float4 jb4 = sm.cboxAll[start + j];
          float ja = sm.careaAll[start + j];
          bool kf = (j < bs) && (lane < bs) && (lane > j) &&
                    (iou_pre(jb4, ja, ib, ia) > 0.5f);
          unsigned long long rowm = __ballot(kf);
          if (lane == 0) sm.kill[j] = rowm;
        }
        {
          bool dead = false;
          if (lane < bs) {
            for (int jc = wv; jc < nc; jc += 16) {
              if (iou_pre(sm.comm[jc], sm.commA[jc], ib, ia) > 0.5f) { dead = true; break; }
            }
          }
          unsigned long long dm = __ballot(dead);
          if (lane == 0) sm.s_dead[wv] = dm;
        }
        __syncthreads();

        // resolve in wave 0: bit-transpose + peeling (ballot-pure; equivalent
        // to the serial walk by greedy-prefix induction; exact MAXT trunc).
        if (wv == 0) {
          unsigned long long sup = sm.s_dead[0];
          #pragma unroll
          for (int w2 = 1; w2 < 16; ++w2) sup |= sm.s_dead[w2];
          unsigned long long row = sm.kill[lane];
          #pragma unroll
          for (int s5 = 0; s5 < 6; ++s5) {
            const unsigned long long Ms[6] = {
              0x5555555555555555ULL, 0x3333333333333333ULL,
              0x0F0F0F0F0F0F0F0FULL, 0x00FF00FF00FF00FFULL,
              0x0000FFFF0000FFFFULL, 0x00000000FFFFFFFFULL };
            int d = 1 << s5;
            unsigned long long other = __shfl_xor(row, d);
            unsigned long long Mk = Ms[s5];
            row = ((lane & d) == 0) ? ((row & Mk) | ((other & Mk) << d))
                                    : ((row & ~Mk) | ((other & ~Mk) >> d));
          }
          unsigned long long col = row;   // col_i = {j<i : j would kill i}

          unsigned long long alive = ~sup;
          if (bs < 64) alive &= (1ULL << bs) - 1ULL;
          unsigned long long pend = alive, chosen = 0ULL;
          while (pend) {
            bool rdy_b = ((col & pend) == 0ULL);
            unsigned long long rdy = __ballot(rdy_b) & pend;
            bool kld_b = ((col & chosen) != 0ULL);
            unsigned long long kl = __ballot(kld_b);
            chosen |= rdy & ~kl;
            pend &= ~rdy;
          }
          int take = MAXT - nc;
          if (__popcll(chosen) > take) {
            bool keep = ((chosen >> lane) & 1ULL) &&
                        (__popcll(chosen & ((1ULL << lane) - 1ULL)) < take);
            chosen = __ballot(keep);
          }
          if ((chosen >> lane) & 1ULL) {
            int rnk = nc + __popcll(chosen & ((1ULL << lane) - 1ULL));
            float4 bb2 = sm.cboxAll[start + lane];
            sm.comm[rnk] = bb2;
            sm.commA[rnk] = sm.careaAll[start + lane];
            sv[rnk] = funord((unsigned)(sm.cbuf[start + lane] >> 32));
            sb[(size_t)rnk * 4 + 0] = bb2.x; sb[(size_t)rnk * 4 + 1] = bb2.y;
            sb[(size_t)rnk * 4 + 2] = bb2.z; sb[(size_t)rnk * 4 + 3] = bb2.w;
          }
          if (lane == 0) sm.s_ncomm = nc + __popcll(chosen);
        }
        __syncthreads();
        start += bs;
      }
    }
    bhi = blo - 1;
  }

  // remaining steps invalid -> sel_val = NEG (boxes never read for these)
  int T = sm.s_ncomm;
  for (int j2 = T + tid; j2 < MAXT; j2 += NTH) sv[j2] = NEGV;
}

// ---- merge (fused rank+scatter, round-11/12 verbatim): block (b,sc) loads
// all 4200 batch keys into LDS; 5 threads per entry split the 21 class binary
// searches; integer LDS atomicAdd partial sums (order-independent => exact,
// deterministic); 200 threads scatter. rank = sum over classes of
// count(key > mykey); ranks are a permutation of 0..4199.
__global__ __launch_bounds__(NTH) void merge2_kernel(
    const float* __restrict__ sel_val, const float* __restrict__ sel_box,
    float* __restrict__ out)
{
  __shared__ Smem sm;
  const int bc = blockIdx.x;
  const int b = bc / C_, sc = bc % C_;
  const int tid = threadIdx.x;
  int* s_rank = reinterpret_cast<int*>(sm.cboxAll);   // aliased scratch

  for (int i = tid; i < NENT; i += NTH) {
    float v = sel_val[(size_t)b * NENT + i];
    unsigned long long key = ((unsigned long long)ford(v) << 32) |
                             (unsigned)(0xFFFFFFFFu - (unsigned)i);
    if (i < UCAP) sm.ukeys[i] = key; else sm.cbuf[i - UCAP] = key;
  }
  if (tid < MAXT) s_rank[tid] = 0;
  __syncthreads();

  auto klds = [&](int i) -> unsigned long long {
    return (i < UCAP) ? sm.ukeys[i] : sm.cbuf[i - UCAP];
  };

  if (tid < 1000) {
    int q = tid / MAXT, t = tid - q * MAXT;   // q in [0,5), t in [0,200)
    int e = sc * MAXT + t;
    unsigned long long mykey = klds(e);
    int part = 0;
    for (int cc = q; cc < C_; cc += 5) {
      int lo = 0, hi = MAXT;
      while (lo < hi) {
        int mid = (lo + hi) >> 1;
        if (klds(cc * MAXT + mid) > mykey) lo = mid + 1; else hi = mid;
      }
      part += lo;
    }
    atomicAdd(&s_rank[t], part);
  }
  __syncthreads();

  if (tid < MAXT) {
    int t = tid;
    int e = sc * MAXT + t;
    int rank = s_rank[t];
    if (rank < MAXT) {
      float* obx = out + (size_t)b * MAXT * 4;                       // bboxes
      float* olb = out + (size_t)B_ * MAXT * 4 + (size_t)b * MAXT;   // labels
      float* osc = out + (size_t)B_ * MAXT * 5 + (size_t)b * MAXT;   // scores
      float v = funord((unsigned)(klds(e) >> 32));
      if (v > NEGV * 0.5f) {
        osc[rank] = v;
        olb[rank] = (float)sc;
        const float* bp = sel_box + ((size_t)b * NENT + e) * 4;
        obx[rank * 4 + 0] = bp[0]; obx[rank * 4 + 1] = bp[1];
        obx[rank * 4 + 2] = bp[2]; obx[rank * 4 + 3] = bp[3];
      } else {
        osc[rank] = 0.f; olb[rank] = 0.f;
        obx[rank * 4 + 0] = 0.f; obx[rank * 4 + 1] = 0.f;
        obx[rank * 4 + 2] = 0.f; obx[rank * 4 + 3] = 0.f;
      }
    }
  }
}

extern "C" void kernel_launch(void* const* d_in, const int* in_sizes, int n_in,
                              void* d_out, int out_size, void* d_ws, size_t ws_size,
                              hipStream_t stream)
{
  const float* roi    = (const float*)d_in[0];  // (8,6000,4)
  const float* deltas = (const float*)d_in[1];  // (8,6000,84)
  const float* probs  = (const float*)d_in[2];  // (8,6000,21)
  float* out = (float*)d_out;                   // 6400 + 1600 + 1600 floats
  float* ws  = (float*)d_ws;

  // ws layout (floats): sel_val[33600] | sel_box[134400] | probsT[1008000]
  float* sel_val = ws;
  float* sel_box = ws + (size_t)B_ * NENT;
  float* probsT  = ws + (size_t)B_ * NENT * 5;
  size_t need_mid = ((size_t)B_ * NENT * 5 + (size_t)B_ * C_ * N_) * sizeof(float);
  bool haveT = (ws_size >= need_mid);

  const float* probsT_arg = haveT ? probsT : nullptr;
  if (haveT)
    prep_kernel<<<dim3((B_ * N_ + 255) / 256), dim3(256), 0, stream>>>(probs, probsT);
  nms_kernel<<<dim3(NBLK), dim3(NTH), 0, stream>>>(
      roi, deltas, probs, probsT_arg, sel_val, sel_box);
  merge2_kernel<<<dim3(NBLK), dim3(NTH), 0, stream>>>(sel_val, sel_box, out);
}